// Round 8
// baseline (179.479 us; speedup 1.0000x reference)
//
#include <hip/hip_runtime.h>
#include <hip/hip_bf16.h>
#include <hip/hip_fp16.h>

typedef __attribute__((ext_vector_type(8))) short short8;
typedef __attribute__((ext_vector_type(4))) float f32x4;

// Problem constants (from reference)
constexpr int NN = 50000;   // nodes
constexpr int NE = 800000;  // edges
constexpr int FN = 64;      // node feat
constexpr int FE = 32;      // edge feat
constexpr int FG = 32;      // global feat
constexpr int OD = 64;      // out dim
constexpr int NG = 256;     // graphs

constexpr int SCAN_B = 256;
constexpr int NBLK = (NN + SCAN_B - 1) / SCAN_B;  // 196

constexpr int NWIN_E = NE / 16;                   // 50000 edge windows (exact)
constexpr int MS_BLOCKS = 2048;
constexpr int MS_WAVES  = MS_BLOCKS * 4;          // 8192 waves, ~6 windows each
constexpr int NWIN_N = NN / 16;                   // 3125 node windows (exact)
constexpr int NODE_BLOCKS = 782;
constexpr int NODE_WAVES  = NODE_BLOCKS * 4;

static __device__ __forceinline__ unsigned pack_bf16(float a, float b) {
    __hip_bfloat162 h = __float22bfloat162_rn(float2{a, b});
    return *reinterpret_cast<unsigned*>(&h);
}

// ---------------------------------------------------------------------------
// x (f32) -> x_bf16 table (50000 x 64)
// ---------------------------------------------------------------------------
__global__ __launch_bounds__(256) void k_xcvt(const float* __restrict__ x,
                                              unsigned* __restrict__ xb32) {
    const int i = blockIdx.x * 256 + threadIdx.x;  // per 8 elements
    if (i >= NN * FN / 8) return;
    const float4* p = (const float4*)(x + (size_t)i * 8);
    float4 f0 = p[0], f1 = p[1];
    uint4 o;
    o.x = pack_bf16(f0.x, f0.y);
    o.y = pack_bf16(f0.z, f0.w);
    o.z = pack_bf16(f1.x, f1.y);
    o.w = pack_bf16(f1.z, f1.w);
    ((uint4*)xb32)[i] = o;
}

// ---------------------------------------------------------------------------
// uW2b[g][j] = b2[j] + u[g]·W2_u[:,j]   (exact f32)
// ---------------------------------------------------------------------------
__global__ __launch_bounds__(256) void k_uw2(const float* __restrict__ u,
                                             const float* __restrict__ W2,
                                             const float* __restrict__ b2,
                                             float* __restrict__ uW2b) {
    const int lane = threadIdx.x & 63;
    float wcol[FG];
#pragma unroll
    for (int k = 0; k < FG; ++k) wcol[k] = W2[(FN + OD + k) * OD + lane];
    const float bias = b2[lane];

    int g = (blockIdx.x * blockDim.x + threadIdx.x) >> 6;
    g = __builtin_amdgcn_readfirstlane(g);
    if (g >= NG) return;

    const float* __restrict__ urow = u + (size_t)g * FG;
    float acc = bias;
#pragma unroll
    for (int k = 0; k < FG; ++k) acc = fmaf(urow[k], wcol[k], acc);
    uW2b[(size_t)g * OD + lane] = acc;
}

// ---------------------------------------------------------------------------
// Histogram of dst + 3-step exclusive scan (unpadded counts).
// ---------------------------------------------------------------------------
__global__ __launch_bounds__(256) void k_hist(const int* __restrict__ ei,
                                              int* __restrict__ cnt) {
    const int e = blockIdx.x * blockDim.x + threadIdx.x;
    if (e < NE) atomicAdd(&cnt[ei[e]], 1);
}

__global__ __launch_bounds__(SCAN_B) void k_scan1(const int* __restrict__ cnt,
                                                  int* __restrict__ start,
                                                  int* __restrict__ bsum) {
    __shared__ int lds[SCAN_B];
    const int i = blockIdx.x * SCAN_B + threadIdx.x;
    const int v = (i < NN) ? cnt[i] : 0;
    lds[threadIdx.x] = v;
    __syncthreads();
#pragma unroll
    for (int off = 1; off < SCAN_B; off <<= 1) {
        int t = (threadIdx.x >= off) ? lds[threadIdx.x - off] : 0;
        __syncthreads();
        lds[threadIdx.x] += t;
        __syncthreads();
    }
    const int incl = lds[threadIdx.x];
    if (i < NN) start[i] = incl - v;  // exclusive within block
    if (threadIdx.x == SCAN_B - 1) bsum[blockIdx.x] = incl;
}

__global__ __launch_bounds__(SCAN_B) void k_scan2(const int* __restrict__ bsum,
                                                  int* __restrict__ bscan) {
    __shared__ int lds[SCAN_B];
    const int i = threadIdx.x;
    const int v = (i < NBLK) ? bsum[i] : 0;
    lds[i] = v;
    __syncthreads();
#pragma unroll
    for (int off = 1; off < SCAN_B; off <<= 1) {
        int t = (i >= off) ? lds[i - off] : 0;
        __syncthreads();
        lds[i] += t;
        __syncthreads();
    }
    if (i < NBLK) bscan[i] = lds[i] - v;
}

__global__ __launch_bounds__(SCAN_B) void k_scan3(int* __restrict__ start,
                                                  const int* __restrict__ bscan,
                                                  const int* __restrict__ cnt,
                                                  int* __restrict__ cursor) {
    const int i = blockIdx.x * SCAN_B + threadIdx.x;
    if (i < NN) {
        const int s = start[i] + bscan[blockIdx.x];
        start[i] = s;
        cursor[i] = s;
        if (i == NN - 1) start[NN] = s + cnt[i];  // == NE
    }
}

// ---------------------------------------------------------------------------
// Slot assignment: slot[e] = start[dst] + arrival rank. Moves the 800k
// atomic-with-return ops OUT of the MFMA hot loop; coalesced slot write.
// ---------------------------------------------------------------------------
__global__ __launch_bounds__(256) void k_slot(const int* __restrict__ ei,
                                              int* __restrict__ cursor,
                                              int* __restrict__ slotb) {
    const int e = blockIdx.x * blockDim.x + threadIdx.x;
    if (e < NE) {
        const int pos = atomicAdd(&cursor[ei[e]], 1);
        slotb[e] = pos;
    }
}

// ---------------------------------------------------------------------------
// Edge-major message computation + scatter. All reads coalesced except the
// L2/L3-resident xb table; slots precomputed (no atomics here):
//   window = 16 consecutive edges; msg = relu([x_bf16[src] | ea] @ W1 + b1)
//   store msg row as f16 into mbuf[slot[e]]
//   (column-permuted layout: f16 index slot*64 + c*4 + b holds col c+16b,
//    so each 16-lane group's store is one contiguous 128 B line).
// Fragment layouts (mfma_f32_16x16x32_bf16), verified rounds 2-6:
//   A: row = lane&15, k = 8*(lane>>4)+i ; B: col = lane&15, same k
//   C: col = lane&15, row = (lane>>4)*4 + q
// ---------------------------------------------------------------------------
__global__ __launch_bounds__(256) void k_msgscat(const int* __restrict__ ei,
                                                 const float* __restrict__ ea,
                                                 const unsigned short* __restrict__ xb,
                                                 const float* __restrict__ W1,
                                                 const float* __restrict__ b1,
                                                 const int* __restrict__ slotb,
                                                 unsigned short* __restrict__ mbuf) {
    const int l = threadIdx.x & 63;
    const int g = l >> 4;
    const int c = l & 15;

    // W1 B-fragments: wf[t][b] covers k = 32t.., cols 16b..16b+15
    short8 wf[3][4];
#pragma unroll
    for (int t = 0; t < 3; ++t)
#pragma unroll
        for (int b = 0; b < 4; ++b)
#pragma unroll
            for (int i = 0; i < 8; i += 2) {
                const int k = 32 * t + 8 * g + i;
                const unsigned p = pack_bf16(W1[k * OD + (c + 16 * b)],
                                             W1[(k + 1) * OD + (c + 16 * b)]);
                ((unsigned*)&wf[t][b])[i / 2] = p;
            }
    float bias[4];
#pragma unroll
    for (int b = 0; b < 4; ++b) bias[b] = b1[c + 16 * b];

    int wv = (blockIdx.x * blockDim.x + threadIdx.x) >> 6;
    wv = __builtin_amdgcn_readfirstlane(wv);

    for (int w = wv; w < NWIN_E; w += MS_WAVES) {
        const int e = w * 16 + c;            // this lane's edge (dup over g)
        const int src = ei[NE + e];          // coalesced

        // slots for the 4 rows this lane's row-group owns (broadcast loads)
        int pr[4];
#pragma unroll
        for (int q = 0; q < 4; ++q) pr[q] = slotb[w * 16 + 4 * g + q];

        // A fragments: chunks 0,1 = x_bf16[src] (gather), chunk 2 = cvt(ea[e])
        short8 a0, a1, a2;
        {
            const uint4* xr = (const uint4*)(xb + (size_t)src * FN);
            uint4 q0 = xr[g];
            uint4 q1 = xr[4 + g];
            a0 = *(short8*)&q0;
            a1 = *(short8*)&q1;
        }
        {
            const float4* er = (const float4*)(ea + (size_t)e * FE);  // coalesced
            float4 e0 = er[2 * g], e1 = er[2 * g + 1];
            uint4 q2;
            q2.x = pack_bf16(e0.x, e0.y);
            q2.y = pack_bf16(e0.z, e0.w);
            q2.z = pack_bf16(e1.x, e1.y);
            q2.w = pack_bf16(e1.z, e1.w);
            a2 = *(short8*)&q2;
        }

        f32x4 accb[4];
#pragma unroll
        for (int b = 0; b < 4; ++b) {
            f32x4 acc = {0.f, 0.f, 0.f, 0.f};
            acc = __builtin_amdgcn_mfma_f32_16x16x32_bf16(a0, wf[0][b], acc, 0, 0, 0);
            acc = __builtin_amdgcn_mfma_f32_16x16x32_bf16(a1, wf[1][b], acc, 0, 0, 0);
            acc = __builtin_amdgcn_mfma_f32_16x16x32_bf16(a2, wf[2][b], acc, 0, 0, 0);
            accb[b] = acc;
        }

        // store: row r = 4g+q of the window; slot pr[q]; 16 lanes -> 128 B line
#pragma unroll
        for (int q = 0; q < 4; ++q) {
            const float v0 = fmaxf(accb[0][q] + bias[0], 0.0f);
            const float v1 = fmaxf(accb[1][q] + bias[1], 0.0f);
            const float v2 = fmaxf(accb[2][q] + bias[2], 0.0f);
            const float v3 = fmaxf(accb[3][q] + bias[3], 0.0f);
            const __half2 h01 = __float22half2_rn(float2{v0, v1});
            const __half2 h23 = __float22half2_rn(float2{v2, v3});
            uint2 out;
            out.x = *reinterpret_cast<const unsigned*>(&h01);
            out.y = *reinterpret_cast<const unsigned*>(&h23);
            *reinterpret_cast<uint2*>(mbuf + (size_t)pr[q] * 64 + c * 4) = out;
        }
    }
}

// ---------------------------------------------------------------------------
// Segment reduce, 256 B per load instruction: lane = (row parity, col-pair).
//   aggb[n][sc] = bf16( sum over node n's mbuf rows, slot-col sc )
// aggb stays in slot-column order; k_nodem permutes W2 rows to match.
// ---------------------------------------------------------------------------
__global__ __launch_bounds__(256) void k_segred(const unsigned* __restrict__ mb32,
                                                const int* __restrict__ start,
                                                unsigned* __restrict__ aggb32) {
    const int l = threadIdx.x & 63;
    const int half = l >> 5;   // 0: even rows, 1: odd rows
    const int q = l & 31;      // col-pair index (slot-cols 2q, 2q+1)
    int n = (blockIdx.x * blockDim.x + threadIdx.x) >> 6;
    n = __builtin_amdgcn_readfirstlane(n);
    if (n >= NN) return;

    const int r0 = start[n];
    const int r1 = start[n + 1];

    float c0 = 0.0f, c1 = 0.0f;
    int r = r0;
#pragma unroll 4
    for (; r + 1 < r1; r += 2) {
        const unsigned uu = mb32[(size_t)(r + half) * 32 + q];
        const __half2 h = *reinterpret_cast<const __half2*>(&uu);
        const float2 f = __half22float2(h);
        c0 += f.x;
        c1 += f.y;
    }
    if (r < r1 && half == 0) {  // odd tail row
        const unsigned uu = mb32[(size_t)r * 32 + q];
        const __half2 h = *reinterpret_cast<const __half2*>(&uu);
        const float2 f = __half22float2(h);
        c0 += f.x;
        c1 += f.y;
    }
    c0 += __shfl_xor(c0, 32);
    c1 += __shfl_xor(c1, 32);
    if (half == 0) aggb32[(size_t)n * 32 + q] = pack_bf16(c0, c1);
}

// ---------------------------------------------------------------------------
// Node MLP via MFMA: out = relu([x_bf16 | agg] @ W2[0:128] + uW2b[batch])
// agg chunks are in slot-column order sc; true col t(sc) = (sc>>2)+16*(sc&3),
// compensated here by permuting the W2 row when building B-fragments.
// ---------------------------------------------------------------------------
__global__ __launch_bounds__(256) void k_nodem(const unsigned short* __restrict__ xb,
                                               const unsigned short* __restrict__ aggb,
                                               const int* __restrict__ bat,
                                               const float* __restrict__ uW2b,
                                               const float* __restrict__ W2,
                                               float* __restrict__ out) {
    const int l = threadIdx.x & 63;
    const int g = l >> 4;
    const int c = l & 15;

    short8 wf[4][4];
#pragma unroll
    for (int t = 0; t < 4; ++t)
#pragma unroll
        for (int b = 0; b < 4; ++b)
#pragma unroll
            for (int i = 0; i < 8; i += 2) {
                const int col = c + 16 * b;
                unsigned p;
                if (t < 2) {
                    const int k = 32 * t + 8 * g + i;
                    p = pack_bf16(W2[k * OD + col], W2[(k + 1) * OD + col]);
                } else {
                    const int sc0 = 32 * (t - 2) + 8 * g + i;
                    const int sc1 = sc0 + 1;
                    const int k0 = FN + ((sc0 >> 2) + 16 * (sc0 & 3));
                    const int k1 = FN + ((sc1 >> 2) + 16 * (sc1 & 3));
                    p = pack_bf16(W2[k0 * OD + col], W2[k1 * OD + col]);
                }
                ((unsigned*)&wf[t][b])[i / 2] = p;
            }

    int wv = (blockIdx.x * blockDim.x + threadIdx.x) >> 6;
    wv = __builtin_amdgcn_readfirstlane(wv);

    for (int w = wv; w < NWIN_N; w += NODE_WAVES) {
        const int n0 = w * 16;
        const uint4* xr = (const uint4*)(xb + (size_t)(n0 + c) * FN);
        const uint4* ar = (const uint4*)(aggb + (size_t)(n0 + c) * OD);
        uint4 qx0 = xr[g], qx1 = xr[4 + g];
        uint4 qa0 = ar[g], qa1 = ar[4 + g];
        short8 a0 = *(short8*)&qx0, a1 = *(short8*)&qx1;
        short8 a2 = *(short8*)&qa0, a3 = *(short8*)&qa1;

        int bq[4];
#pragma unroll
        for (int q = 0; q < 4; ++q) bq[q] = bat[n0 + g * 4 + q];

#pragma unroll
        for (int b = 0; b < 4; ++b) {
            f32x4 acc = {0.f, 0.f, 0.f, 0.f};
            acc = __builtin_amdgcn_mfma_f32_16x16x32_bf16(a0, wf[0][b], acc, 0, 0, 0);
            acc = __builtin_amdgcn_mfma_f32_16x16x32_bf16(a1, wf[1][b], acc, 0, 0, 0);
            acc = __builtin_amdgcn_mfma_f32_16x16x32_bf16(a2, wf[2][b], acc, 0, 0, 0);
            acc = __builtin_amdgcn_mfma_f32_16x16x32_bf16(a3, wf[3][b], acc, 0, 0, 0);
#pragma unroll
            for (int q = 0; q < 4; ++q) {
                const int n = n0 + g * 4 + q;
                const float val = acc[q] + uW2b[(size_t)bq[q] * OD + c + 16 * b];
                out[(size_t)n * OD + c + 16 * b] = fmaxf(val, 0.0f);
            }
        }
    }
}

// ---------------------------------------------------------------------------
extern "C" void kernel_launch(void* const* d_in, const int* in_sizes, int n_in,
                              void* d_out, int out_size, void* d_ws, size_t ws_size,
                              hipStream_t stream) {
    const float* x    = (const float*)d_in[0];   // (50000, 64)
    const int*   ei   = (const int*)d_in[1];     // (2, 800000)
    const float* ea   = (const float*)d_in[2];   // (800000, 32)
    const float* u    = (const float*)d_in[3];   // (256, 32)
    const int*   bat  = (const int*)d_in[4];     // (50000,)
    const float* W1   = (const float*)d_in[5];   // (96, 64)
    const float* b1   = (const float*)d_in[6];   // (64,)
    const float* W2   = (const float*)d_in[7];   // (160, 64)
    const float* b2   = (const float*)d_in[8];   // (64,)
    float* out = (float*)d_out;                  // (50000, 64)

    // workspace layout (~119 MB; mbuf dominates)
    char* ws = (char*)d_ws;
    auto alloc = [&](size_t bytes) {
        char* p = ws;
        ws += (bytes + 255) & ~size_t(255);
        return p;
    };
    unsigned short* xb   = (unsigned short*)alloc((size_t)NN * FN * 2);   // 6.4 MB
    unsigned short* aggb = (unsigned short*)alloc((size_t)NN * OD * 2);   // 6.4 MB
    float* uW2b    = (float*)alloc((size_t)NG * OD * sizeof(float));
    int*   cnt     = (int*)alloc((size_t)NN * sizeof(int));
    int*   start   = (int*)alloc((size_t)(NN + 1) * sizeof(int));
    int*   cursor  = (int*)alloc((size_t)NN * sizeof(int));
    int*   bsum    = (int*)alloc((size_t)NBLK * sizeof(int));
    int*   bscan   = (int*)alloc((size_t)NBLK * sizeof(int));
    int*   slotb   = (int*)alloc((size_t)NE * sizeof(int));               // 3.2 MB
    unsigned short* mbuf = (unsigned short*)alloc((size_t)NE * OD * 2);   // 102.4 MB

    hipMemsetAsync(cnt, 0, (size_t)NN * sizeof(int), stream);

    // precomputes
    k_xcvt<<<dim3((NN * FN / 8 + 255) / 256), dim3(256), 0, stream>>>(x, (unsigned*)xb);
    k_uw2<<<dim3((NG * 64 + 255) / 256), dim3(256), 0, stream>>>(u, W2, b2, uW2b);

    // dst histogram + exclusive scan + slot assignment
    k_hist<<<dim3((NE + 255) / 256), dim3(256), 0, stream>>>(ei, cnt);
    k_scan1<<<dim3(NBLK), dim3(SCAN_B), 0, stream>>>(cnt, start, bsum);
    k_scan2<<<dim3(1), dim3(SCAN_B), 0, stream>>>(bsum, bscan);
    k_scan3<<<dim3(NBLK), dim3(SCAN_B), 0, stream>>>(start, bscan, cnt, cursor);
    k_slot<<<dim3((NE + 255) / 256), dim3(256), 0, stream>>>(ei, cursor, slotb);

    // edge-major message MFMA + scatter (coalesced reads, random line writes)
    k_msgscat<<<dim3(MS_BLOCKS), dim3(256), 0, stream>>>(ei, ea, xb, W1, b1, slotb, mbuf);

    // wide sequential segment reduce
    k_segred<<<dim3((NN * 64 + 255) / 256), dim3(256), 0, stream>>>((const unsigned*)mbuf, start, (unsigned*)aggb);

    // node MLP (MFMA)
    k_nodem<<<dim3(NODE_BLOCKS), dim3(256), 0, stream>>>(xb, aggb, bat, uW2b, W2, out);
}

// Round 9
// 168.795 us; speedup vs baseline: 1.0633x; 1.0633x over previous
//
#include <hip/hip_runtime.h>
#include <hip/hip_bf16.h>

typedef __attribute__((ext_vector_type(8))) short short8;
typedef __attribute__((ext_vector_type(4))) float f32x4;

// Problem constants (from reference)
constexpr int NN = 50000;   // nodes
constexpr int NE = 800000;  // edges
constexpr int FN = 64;      // node feat
constexpr int FE = 32;      // edge feat
constexpr int FG = 32;      // global feat
constexpr int OD = 64;      // out dim
constexpr int NG = 256;     // graphs

constexpr int SCAN_B = 256;
constexpr int NBLK = (NN + SCAN_B - 1) / SCAN_B;        // 196

constexpr int SLOTS_MAX = NE + 15 * NN;                 // 1.55M padded slots
constexpr int NWIN_MAX  = SLOTS_MAX / 16;               // 96875 windows max

constexpr int XCVT_BLOCKS = (NN * FN / 8 + 255) / 256;  // 1563
constexpr int PRE_BLOCKS  = XCVT_BLOCKS + (NG * 64) / 256;  // +64

constexpr int AGG_BLOCKS = 2048;
constexpr int AGG_WAVES  = AGG_BLOCKS * 4;              // 8192 waves
constexpr int NWIN_N = NN / 16;                         // 3125
constexpr int NODE_BLOCKS = 782;
constexpr int NODE_WAVES  = NODE_BLOCKS * 4;

static __device__ __forceinline__ unsigned pack_bf16(float a, float b) {
    __hip_bfloat162 h = __float22bfloat162_rn(float2{a, b});
    return *reinterpret_cast<unsigned*>(&h);
}

// ---------------------------------------------------------------------------
// Fused precompute: x->bf16 table, uW2b = b2 + u@W2_u (exact f32), zero cnt.
// ---------------------------------------------------------------------------
__global__ __launch_bounds__(256) void k_pre(const float* __restrict__ x,
                                             unsigned* __restrict__ xb32,
                                             const float* __restrict__ u,
                                             const float* __restrict__ W2,
                                             const float* __restrict__ b2,
                                             float* __restrict__ uW2b,
                                             int* __restrict__ cnt) {
    if (blockIdx.x >= XCVT_BLOCKS) {  // uW2b part
        const int lane = threadIdx.x & 63;
        float wcol[FG];
#pragma unroll
        for (int k = 0; k < FG; ++k) wcol[k] = W2[(FN + OD + k) * OD + lane];
        const float bias = b2[lane];
        int g = ((blockIdx.x - XCVT_BLOCKS) * 256 + threadIdx.x) >> 6;
        g = __builtin_amdgcn_readfirstlane(g);
        if (g >= NG) return;
        const float* __restrict__ urow = u + (size_t)g * FG;
        float acc = bias;
#pragma unroll
        for (int k = 0; k < FG; ++k) acc = fmaf(urow[k], wcol[k], acc);
        uW2b[(size_t)g * OD + lane] = acc;
        return;
    }
    const int i = blockIdx.x * 256 + threadIdx.x;
    if (i < NN) cnt[i] = 0;
    if (i >= NN * FN / 8) return;
    const float4* p = (const float4*)(x + (size_t)i * 8);
    float4 f0 = p[0], f1 = p[1];
    uint4 o;
    o.x = pack_bf16(f0.x, f0.y);
    o.y = pack_bf16(f0.z, f0.w);
    o.z = pack_bf16(f1.x, f1.y);
    o.w = pack_bf16(f1.z, f1.w);
    ((uint4*)xb32)[i] = o;
}

// ---------------------------------------------------------------------------
// Histogram of dst.
// ---------------------------------------------------------------------------
__global__ __launch_bounds__(256) void k_hist(const int* __restrict__ ei,
                                              int* __restrict__ cnt) {
    const int e = blockIdx.x * blockDim.x + threadIdx.x;
    if (e < NE) atomicAdd(&cnt[ei[e]], 1);
}

// ---------------------------------------------------------------------------
// Scan step 1 over PADDED counts (ceil16): block-local exclusive + block sums.
// ---------------------------------------------------------------------------
__global__ __launch_bounds__(SCAN_B) void k_scan1(const int* __restrict__ cnt,
                                                  int* __restrict__ pstart,
                                                  int* __restrict__ bsum) {
    __shared__ int lds[SCAN_B];
    const int i = blockIdx.x * SCAN_B + threadIdx.x;
    const int v = (i < NN) ? (((cnt[i] + 15) >> 4) << 4) : 0;
    lds[threadIdx.x] = v;
    __syncthreads();
#pragma unroll
    for (int off = 1; off < SCAN_B; off <<= 1) {
        int t = (threadIdx.x >= off) ? lds[threadIdx.x - off] : 0;
        __syncthreads();
        lds[threadIdx.x] += t;
        __syncthreads();
    }
    const int incl = lds[threadIdx.x];
    if (i < NN) pstart[i] = incl - v;  // exclusive within block
    if (threadIdx.x == SCAN_B - 1) bsum[blockIdx.x] = incl;
}

// ---------------------------------------------------------------------------
// Scan steps 2+3 fused: every block scans the 196 block sums in LDS, adds its
// offset, finalizes pstart/cursor, and emits per-window segment ends (winend)
// so the agg kernel can clamp+mask without any pad-fill writes.
// ---------------------------------------------------------------------------
__global__ __launch_bounds__(SCAN_B) void k_scan23(int* __restrict__ pstart,
                                                   const int* __restrict__ bsum,
                                                   const int* __restrict__ cnt,
                                                   int* __restrict__ cursor,
                                                   int* __restrict__ winend) {
    __shared__ int lds[SCAN_B];
    const int t = threadIdx.x;
    lds[t] = (t < NBLK) ? bsum[t] : 0;
    __syncthreads();
#pragma unroll
    for (int off = 1; off < SCAN_B; off <<= 1) {
        int tv = (t >= off) ? lds[t - off] : 0;
        __syncthreads();
        lds[t] += tv;
        __syncthreads();
    }
    const int boff = (blockIdx.x == 0) ? 0 : lds[blockIdx.x - 1];

    const int i = blockIdx.x * SCAN_B + t;
    if (i < NN) {
        const int cn = cnt[i];
        const int pc = ((cn + 15) >> 4) << 4;
        const int s = pstart[i] + boff;
        pstart[i] = s;
        cursor[i] = s;
        const int end = s + cn;
        const int w0 = s >> 4;
        const int w1 = (s + pc) >> 4;
        for (int w = w0; w < w1; ++w) winend[w] = end;
        if (i == NN - 1) pstart[NN] = s + pc;
    }
}

// ---------------------------------------------------------------------------
// Scatter {src, e} into padded dst-sorted bucket slots.
// ---------------------------------------------------------------------------
__global__ __launch_bounds__(256) void k_scatter(const int* __restrict__ ei,
                                                 int* __restrict__ cursor,
                                                 int2* __restrict__ bucket) {
    const int e = blockIdx.x * blockDim.x + threadIdx.x;
    if (e < NE) {
        const int dst = ei[e];
        const int src = ei[NE + e];
        const int pos = atomicAdd(&cursor[dst], 1);
        bucket[pos] = make_int2(src, e);
    }
}

// ---------------------------------------------------------------------------
// Fused gather + MFMA + masked window reduce, TWO windows per iteration:
// 10 independent load instructions (2 bucket + 4 xb + 4 ea) issue before any
// MFMA -> ~100+ cache lines in flight per wave (outstanding-miss fix; r5 had
// ~5 loads/wave and capped at 1.78 TB/s per the latency*BW arithmetic).
//   partial[w][j] = sum over valid rows of relu([xb[src] | ea] @ W1 + b1)[j]
// Pad slots are never read (clamp to end-1) and never counted (row mask).
// Fragment layouts (mfma_f32_16x16x32_bf16), verified rounds 2-7:
//   A: row = lane&15, k = 8*(lane>>4)+i ; B: col = lane&15, same k
//   C: col = lane&15, row = (lane>>4)*4 + q
// ---------------------------------------------------------------------------
__global__ __launch_bounds__(256) void k_aggw2(const int2* __restrict__ bucket,
                                               const float* __restrict__ ea,
                                               const unsigned short* __restrict__ xb,
                                               const float* __restrict__ W1,
                                               const float* __restrict__ b1,
                                               const int* __restrict__ pstart,
                                               const int* __restrict__ winend,
                                               float* __restrict__ partial) {
    const int l = threadIdx.x & 63;
    const int g = l >> 4;
    const int c = l & 15;

    // W1 B-fragments: wf[t][b] covers k = 32t.., cols 16b..16b+15
    short8 wf[3][4];
#pragma unroll
    for (int t = 0; t < 3; ++t)
#pragma unroll
        for (int b = 0; b < 4; ++b)
#pragma unroll
            for (int i = 0; i < 8; i += 2) {
                const int k = 32 * t + 8 * g + i;
                const unsigned p = pack_bf16(W1[k * OD + (c + 16 * b)],
                                             W1[(k + 1) * OD + (c + 16 * b)]);
                ((unsigned*)&wf[t][b])[i / 2] = p;
            }
    float bias[4];
#pragma unroll
    for (int b = 0; b < 4; ++b) bias[b] = b1[c + 16 * b];

    const int nwin = pstart[NN] >> 4;

    int wv = (blockIdx.x * blockDim.x + threadIdx.x) >> 6;
    wv = __builtin_amdgcn_readfirstlane(wv);

    auto computeWin = [&](int w, int end, uint4 q0, uint4 q1,
                          float4 e0, float4 e1) {
        short8 a0 = *(short8*)&q0;
        short8 a1 = *(short8*)&q1;
        uint4 q2;
        q2.x = pack_bf16(e0.x, e0.y);
        q2.y = pack_bf16(e0.z, e0.w);
        q2.z = pack_bf16(e1.x, e1.y);
        q2.w = pack_bf16(e1.z, e1.w);
        short8 a2 = *(short8*)&q2;

        float sv[4];
#pragma unroll
        for (int b = 0; b < 4; ++b) {
            f32x4 acc = {0.f, 0.f, 0.f, 0.f};
            acc = __builtin_amdgcn_mfma_f32_16x16x32_bf16(a0, wf[0][b], acc, 0, 0, 0);
            acc = __builtin_amdgcn_mfma_f32_16x16x32_bf16(a1, wf[1][b], acc, 0, 0, 0);
            acc = __builtin_amdgcn_mfma_f32_16x16x32_bf16(a2, wf[2][b], acc, 0, 0, 0);
            float s = 0.0f;
#pragma unroll
            for (int q = 0; q < 4; ++q) {
                const int row = w * 16 + 4 * g + q;
                const float v = fmaxf(acc[q] + bias[b], 0.0f);
                s += (row < end) ? v : 0.0f;
            }
            s += __shfl_xor(s, 16);
            s += __shfl_xor(s, 32);
            sv[b] = s;
        }
        float v = sv[0];
        v = (g == 1) ? sv[1] : v;
        v = (g == 2) ? sv[2] : v;
        v = (g == 3) ? sv[3] : v;
        partial[(size_t)w * 64 + l] = v;  // l == c + 16g, coalesced
    };

    for (int p = wv; 2 * p < nwin; p += AGG_WAVES) {
        const int wA = 2 * p;
        const int wB = wA + 1;
        const bool hasB = (wB < nwin);

        const int endA = winend[wA];
        const int endB = winend[hasB ? wB : wA];

        int sA = wA * 16 + c;
        if (sA >= endA) sA = endA - 1;          // clamp into real slots
        int sB = wB * 16 + c;
        if (!hasB || sB >= endB) sB = endB - 1;

        const int2 pa = bucket[sA];
        const int2 pb = bucket[sB];

        // issue all 8 payload loads before any compute (independent chains)
        const uint4* xra = (const uint4*)(xb + (size_t)pa.x * FN);
        const uint4 qa0 = xra[g];
        const uint4 qa1 = xra[4 + g];
        const float4* era = (const float4*)(ea + (size_t)pa.y * FE);
        const float4 ea0 = era[2 * g];
        const float4 ea1 = era[2 * g + 1];

        const uint4* xrb = (const uint4*)(xb + (size_t)pb.x * FN);
        const uint4 qb0 = xrb[g];
        const uint4 qb1 = xrb[4 + g];
        const float4* erb = (const float4*)(ea + (size_t)pb.y * FE);
        const float4 eb0 = erb[2 * g];
        const float4 eb1 = erb[2 * g + 1];

        computeWin(wA, endA, qa0, qa1, ea0, ea1);
        if (hasB) computeWin(wB, endB, qb0, qb1, eb0, eb1);
    }
}

// ---------------------------------------------------------------------------
// Reduce windows per node: aggb[n] = bf16( sum partials )  (masking was exact,
// no correction term needed; nodes with zero edges write 0).
// ---------------------------------------------------------------------------
__global__ __launch_bounds__(256) void k_red(const float* __restrict__ partial,
                                             const int* __restrict__ pstart,
                                             unsigned short* __restrict__ aggb) {
    const int l = threadIdx.x & 63;
    int n = (blockIdx.x * blockDim.x + threadIdx.x) >> 6;
    n = __builtin_amdgcn_readfirstlane(n);
    if (n >= NN) return;

    const int w0 = pstart[n] >> 4;
    const int w1 = pstart[n + 1] >> 4;
    float s = 0.0f;
    for (int w = w0; w < w1; ++w) s += partial[(size_t)w * 64 + l];
    __hip_bfloat16 hb = __float2bfloat16(s);
    aggb[(size_t)n * OD + l] = *reinterpret_cast<unsigned short*>(&hb);
}

// ---------------------------------------------------------------------------
// Node MLP via MFMA: out = relu([x_bf16 | agg_bf16] @ W2[0:128] + uW2b[batch])
// ---------------------------------------------------------------------------
__global__ __launch_bounds__(256) void k_nodem(const unsigned short* __restrict__ xb,
                                               const unsigned short* __restrict__ aggb,
                                               const int* __restrict__ bat,
                                               const float* __restrict__ uW2b,
                                               const float* __restrict__ W2,
                                               float* __restrict__ out) {
    const int l = threadIdx.x & 63;
    const int g = l >> 4;
    const int c = l & 15;

    short8 wf[4][4];
#pragma unroll
    for (int t = 0; t < 4; ++t)
#pragma unroll
        for (int b = 0; b < 4; ++b)
#pragma unroll
            for (int i = 0; i < 8; i += 2) {
                const int k = 32 * t + 8 * g + i;
                const unsigned p = pack_bf16(W2[k * OD + (c + 16 * b)],
                                             W2[(k + 1) * OD + (c + 16 * b)]);
                ((unsigned*)&wf[t][b])[i / 2] = p;
            }

    int wv = (blockIdx.x * blockDim.x + threadIdx.x) >> 6;
    wv = __builtin_amdgcn_readfirstlane(wv);

    for (int w = wv; w < NWIN_N; w += NODE_WAVES) {
        const int n0 = w * 16;
        const uint4* xr = (const uint4*)(xb + (size_t)(n0 + c) * FN);
        const uint4* ar = (const uint4*)(aggb + (size_t)(n0 + c) * OD);
        uint4 qx0 = xr[g], qx1 = xr[4 + g];
        uint4 qa0 = ar[g], qa1 = ar[4 + g];
        short8 a0 = *(short8*)&qx0, a1 = *(short8*)&qx1;
        short8 a2 = *(short8*)&qa0, a3 = *(short8*)&qa1;

        int bq[4];
#pragma unroll
        for (int q = 0; q < 4; ++q) bq[q] = bat[n0 + g * 4 + q];

#pragma unroll
        for (int b = 0; b < 4; ++b) {
            f32x4 acc = {0.f, 0.f, 0.f, 0.f};
            acc = __builtin_amdgcn_mfma_f32_16x16x32_bf16(a0, wf[0][b], acc, 0, 0, 0);
            acc = __builtin_amdgcn_mfma_f32_16x16x32_bf16(a1, wf[1][b], acc, 0, 0, 0);
            acc = __builtin_amdgcn_mfma_f32_16x16x32_bf16(a2, wf[2][b], acc, 0, 0, 0);
            acc = __builtin_amdgcn_mfma_f32_16x16x32_bf16(a3, wf[3][b], acc, 0, 0, 0);
#pragma unroll
            for (int q = 0; q < 4; ++q) {
                const int n = n0 + g * 4 + q;
                const float val = acc[q] + uW2b[(size_t)bq[q] * OD + c + 16 * b];
                out[(size_t)n * OD + c + 16 * b] = fmaxf(val, 0.0f);
            }
        }
    }
}

// ---------------------------------------------------------------------------
extern "C" void kernel_launch(void* const* d_in, const int* in_sizes, int n_in,
                              void* d_out, int out_size, void* d_ws, size_t ws_size,
                              hipStream_t stream) {
    const float* x    = (const float*)d_in[0];   // (50000, 64)
    const int*   ei   = (const int*)d_in[1];     // (2, 800000)
    const float* ea   = (const float*)d_in[2];   // (800000, 32)
    const float* u    = (const float*)d_in[3];   // (256, 32)
    const int*   bat  = (const int*)d_in[4];     // (50000,)
    const float* W1   = (const float*)d_in[5];   // (96, 64)
    const float* b1   = (const float*)d_in[6];   // (64,)
    const float* W2   = (const float*)d_in[7];   // (160, 64)
    const float* b2   = (const float*)d_in[8];   // (64,)
    float* out = (float*)d_out;                  // (50000, 64)

    // workspace layout (~51 MB)
    char* ws = (char*)d_ws;
    auto alloc = [&](size_t bytes) {
        char* p = ws;
        ws += (bytes + 255) & ~size_t(255);
        return p;
    };
    unsigned short* xb   = (unsigned short*)alloc((size_t)NN * FN * 2);    // 6.4 MB
    unsigned short* aggb = (unsigned short*)alloc((size_t)NN * OD * 2);    // 6.4 MB
    float* uW2b    = (float*)alloc((size_t)NG * OD * sizeof(float));
    int*   cnt     = (int*)alloc((size_t)NN * sizeof(int));
    int*   pstart  = (int*)alloc((size_t)(NN + 1) * sizeof(int));
    int*   cursor  = (int*)alloc((size_t)NN * sizeof(int));
    int*   bsum    = (int*)alloc((size_t)NBLK * sizeof(int));
    int*   winend  = (int*)alloc((size_t)NWIN_MAX * sizeof(int));          // 0.4 MB
    int2*  bucket  = (int2*)alloc((size_t)SLOTS_MAX * sizeof(int2));       // 12.4 MB
    float* partial = (float*)alloc((size_t)NWIN_MAX * OD * sizeof(float)); // 24.8 MB

    // fused precompute (x->bf16, uW2b, zero cnt) — no memset dispatch needed
    k_pre<<<dim3(PRE_BLOCKS), dim3(256), 0, stream>>>(x, (unsigned*)xb, u, W2, b2, uW2b, cnt);

    // dst histogram + padded exclusive scan (+ per-window segment ends)
    k_hist<<<dim3((NE + 255) / 256), dim3(256), 0, stream>>>(ei, cnt);
    k_scan1<<<dim3(NBLK), dim3(SCAN_B), 0, stream>>>(cnt, pstart, bsum);
    k_scan23<<<dim3(NBLK), dim3(SCAN_B), 0, stream>>>(pstart, bsum, cnt, cursor, winend);

    // scatter {src,e} into dst-sorted padded buckets
    k_scatter<<<dim3((NE + 255) / 256), dim3(256), 0, stream>>>(ei, cursor, bucket);

    // fused gather + MFMA + masked window sums (2 windows / iteration)
    k_aggw2<<<dim3(AGG_BLOCKS), dim3(256), 0, stream>>>(bucket, ea, xb, W1, b1, pstart, winend, partial);

    // per-node reduce of window partials
    k_red<<<dim3((NN * 64 + 255) / 256), dim3(256), 0, stream>>>(partial, pstart, aggb);

    // node MLP (MFMA)
    k_nodem<<<dim3(NODE_BLOCKS), dim3(256), 0, stream>>>(xb, aggb, bat, uW2b, W2, out);
}

// Round 10
// 156.105 us; speedup vs baseline: 1.1497x; 1.0813x over previous
//
#include <hip/hip_runtime.h>
#include <hip/hip_bf16.h>

typedef __attribute__((ext_vector_type(8))) short short8;
typedef __attribute__((ext_vector_type(4))) float f32x4;

// Problem constants (from reference)
constexpr int NN = 50000;   // nodes
constexpr int NE = 800000;  // edges
constexpr int FN = 64;      // node feat
constexpr int FE = 32;      // edge feat
constexpr int FG = 32;      // global feat
constexpr int OD = 64;      // out dim
constexpr int NG = 256;     // graphs

constexpr int SCAN_B = 256;
constexpr int NBLK = (NN + SCAN_B - 1) / SCAN_B;        // 196

// Padded slot capacity: worst case is NE + 15*NN = 1.55M, but pads are
// ~uniform(0..15) per node -> E[total] = NE + 7.5*NN = 1.175M, sigma ~1k.
// 1.35M is a >100-sigma bound; keeps bucket_ea at 86 MB (ws budget).
constexpr int SLOTS_CAP = 1350000;
constexpr int NWIN_CAP  = SLOTS_CAP / 16;               // 84375

constexpr int XCVT_BLOCKS = (NN * FN / 8 + 255) / 256;  // 1563
constexpr int PRE_BLOCKS  = XCVT_BLOCKS + (NG * 64) / 256;  // +64

constexpr int AGG_BLOCKS = 2048;
constexpr int AGG_WAVES  = AGG_BLOCKS * 4;              // 8192 waves
constexpr int NWIN_N = NN / 16;                         // 3125
constexpr int NODE_BLOCKS = 782;
constexpr int NODE_WAVES  = NODE_BLOCKS * 4;

static __device__ __forceinline__ unsigned pack_bf16(float a, float b) {
    __hip_bfloat162 h = __float22bfloat162_rn(float2{a, b});
    return *reinterpret_cast<unsigned*>(&h);
}

// ---------------------------------------------------------------------------
// Fused precompute: x->bf16 table, uW2b = b2 + u@W2_u (exact f32), zero cnt.
// ---------------------------------------------------------------------------
__global__ __launch_bounds__(256) void k_pre(const float* __restrict__ x,
                                             unsigned* __restrict__ xb32,
                                             const float* __restrict__ u,
                                             const float* __restrict__ W2,
                                             const float* __restrict__ b2,
                                             float* __restrict__ uW2b,
                                             int* __restrict__ cnt) {
    if (blockIdx.x >= XCVT_BLOCKS) {  // uW2b part
        const int lane = threadIdx.x & 63;
        float wcol[FG];
#pragma unroll
        for (int k = 0; k < FG; ++k) wcol[k] = W2[(FN + OD + k) * OD + lane];
        const float bias = b2[lane];
        int g = ((blockIdx.x - XCVT_BLOCKS) * 256 + threadIdx.x) >> 6;
        g = __builtin_amdgcn_readfirstlane(g);
        if (g >= NG) return;
        const float* __restrict__ urow = u + (size_t)g * FG;
        float acc = bias;
#pragma unroll
        for (int k = 0; k < FG; ++k) acc = fmaf(urow[k], wcol[k], acc);
        uW2b[(size_t)g * OD + lane] = acc;
        return;
    }
    const int i = blockIdx.x * 256 + threadIdx.x;
    if (i < NN) cnt[i] = 0;
    if (i >= NN * FN / 8) return;
    const float4* p = (const float4*)(x + (size_t)i * 8);
    float4 f0 = p[0], f1 = p[1];
    uint4 o;
    o.x = pack_bf16(f0.x, f0.y);
    o.y = pack_bf16(f0.z, f0.w);
    o.z = pack_bf16(f1.x, f1.y);
    o.w = pack_bf16(f1.z, f1.w);
    ((uint4*)xb32)[i] = o;
}

// ---------------------------------------------------------------------------
// Histogram of dst.
// ---------------------------------------------------------------------------
__global__ __launch_bounds__(256) void k_hist(const int* __restrict__ ei,
                                              int* __restrict__ cnt) {
    const int e = blockIdx.x * blockDim.x + threadIdx.x;
    if (e < NE) atomicAdd(&cnt[ei[e]], 1);
}

// ---------------------------------------------------------------------------
// Scan step 1 over PADDED counts (ceil16): block-local exclusive + block sums.
// ---------------------------------------------------------------------------
__global__ __launch_bounds__(SCAN_B) void k_scan1(const int* __restrict__ cnt,
                                                  int* __restrict__ pstart,
                                                  int* __restrict__ bsum) {
    __shared__ int lds[SCAN_B];
    const int i = blockIdx.x * SCAN_B + threadIdx.x;
    const int v = (i < NN) ? (((cnt[i] + 15) >> 4) << 4) : 0;
    lds[threadIdx.x] = v;
    __syncthreads();
#pragma unroll
    for (int off = 1; off < SCAN_B; off <<= 1) {
        int t = (threadIdx.x >= off) ? lds[threadIdx.x - off] : 0;
        __syncthreads();
        lds[threadIdx.x] += t;
        __syncthreads();
    }
    const int incl = lds[threadIdx.x];
    if (i < NN) pstart[i] = incl - v;  // exclusive within block
    if (threadIdx.x == SCAN_B - 1) bsum[blockIdx.x] = incl;
}

// ---------------------------------------------------------------------------
// Scan steps 2+3 fused: every block re-scans the block sums, finalizes
// pstart/cursor, emits per-window segment ends (winend).
// ---------------------------------------------------------------------------
__global__ __launch_bounds__(SCAN_B) void k_scan23(int* __restrict__ pstart,
                                                   const int* __restrict__ bsum,
                                                   const int* __restrict__ cnt,
                                                   int* __restrict__ cursor,
                                                   int* __restrict__ winend) {
    __shared__ int lds[SCAN_B];
    const int t = threadIdx.x;
    lds[t] = (t < NBLK) ? bsum[t] : 0;
    __syncthreads();
#pragma unroll
    for (int off = 1; off < SCAN_B; off <<= 1) {
        int tv = (t >= off) ? lds[t - off] : 0;
        __syncthreads();
        lds[t] += tv;
        __syncthreads();
    }
    const int boff = (blockIdx.x == 0) ? 0 : lds[blockIdx.x - 1];

    const int i = blockIdx.x * SCAN_B + t;
    if (i < NN) {
        const int cn = cnt[i];
        const int pc = ((cn + 15) >> 4) << 4;
        const int s = pstart[i] + boff;
        pstart[i] = s;
        cursor[i] = s;
        const int end = s + cn;
        const int w0 = s >> 4;
        const int w1 = (s + pc) >> 4;
        for (int w = w0; w < w1; ++w) winend[w] = end;
        if (i == NN - 1) pstart[NN] = s + pc;
    }
}

// ---------------------------------------------------------------------------
// Fat scatter: 4 lanes per edge. Reads ei + ea COALESCED, converts ea to
// bf16 in-register, writes {src} (4 B) and the 64 B bf16 payload to the
// edge's dst-sorted slot. Random writes drain without stalling the wave —
// this moves the randomness off the latency-critical read path for good.
// ---------------------------------------------------------------------------
__global__ __launch_bounds__(256) void k_scat2(const int* __restrict__ ei,
                                               const float* __restrict__ ea,
                                               int* __restrict__ cursor,
                                               int* __restrict__ bucket_src,
                                               uint4* __restrict__ bucket_ea) {
    const int t = blockIdx.x * 256 + threadIdx.x;
    const int e = t >> 2;
    const int p = t & 3;
    if (e >= NE) return;

    const int lane = threadIdx.x & 63;
    const int dst = ei[e];
    int pos = 0;
    if (p == 0) pos = atomicAdd(&cursor[dst], 1);
    pos = __shfl(pos, lane & ~3);
    if (p == 0) bucket_src[pos] = ei[NE + e];

    const float4* er = (const float4*)(ea + (size_t)e * FE) + 2 * p;
    const float4 f0 = er[0];
    const float4 f1 = er[1];
    uint4 o;
    o.x = pack_bf16(f0.x, f0.y);
    o.y = pack_bf16(f0.z, f0.w);
    o.z = pack_bf16(f1.x, f1.y);
    o.w = pack_bf16(f1.z, f1.w);
    bucket_ea[(size_t)pos * 4 + p] = o;
}

// ---------------------------------------------------------------------------
// Window MFMA over dst-sorted slots. ALL streams sequential except the
// xb[src] gather into the 6.4 MB L2-resident table:
//   window w -> slots 16w..16w+15; lane(g,c): payload uint4 at slot*4+g
//   (wave reads exactly 1 KB contiguous), src broadcast, xb row gather.
//   partial(w) = sum over valid rows of relu([xb|ea]@W1 + b1), masked by
//   winend; pad slots clamp to end-1 (never OOB, never counted).
// Partial stored as packed bf16 col-pairs (128 B/window).
// Fragment layouts (mfma_f32_16x16x32_bf16), verified rounds 2-8:
//   A: row = lane&15, k = 8*(lane>>4)+i ; B: col = lane&15, same k
//   C: col = lane&15, row = (lane>>4)*4 + q
// ---------------------------------------------------------------------------
__global__ __launch_bounds__(256) void k_aggw3(const int* __restrict__ bucket_src,
                                               const uint4* __restrict__ bucket_ea,
                                               const unsigned short* __restrict__ xb,
                                               const float* __restrict__ W1,
                                               const float* __restrict__ b1,
                                               const int* __restrict__ pstart,
                                               const int* __restrict__ winend,
                                               unsigned* __restrict__ partial32) {
    const int l = threadIdx.x & 63;
    const int g = l >> 4;
    const int c = l & 15;

    // W1 B-fragments: wf[t][b] covers k = 32t.., cols 16b..16b+15
    short8 wf[3][4];
#pragma unroll
    for (int t = 0; t < 3; ++t)
#pragma unroll
        for (int b = 0; b < 4; ++b)
#pragma unroll
            for (int i = 0; i < 8; i += 2) {
                const int k = 32 * t + 8 * g + i;
                const unsigned p = pack_bf16(W1[k * OD + (c + 16 * b)],
                                             W1[(k + 1) * OD + (c + 16 * b)]);
                ((unsigned*)&wf[t][b])[i / 2] = p;
            }
    float bias[4];
#pragma unroll
    for (int b = 0; b < 4; ++b) bias[b] = b1[c + 16 * b];

    const int nwin = pstart[NN] >> 4;

    int wv = (blockIdx.x * blockDim.x + threadIdx.x) >> 6;
    wv = __builtin_amdgcn_readfirstlane(wv);

    for (int w = wv; w < nwin; w += AGG_WAVES) {
        const int end = winend[w];          // sequential (broadcast)
        int slot = w * 16 + c;
        if (slot >= end) slot = end - 1;    // clamp pads into real slots

        // payload: sequential 1 KB per wave (lane reads its own 16 B chunk)
        const uint4 qe = bucket_ea[(size_t)(w * 16 + c < end ? slot : slot) * 4 + g];
        const int src = bucket_src[slot];   // broadcast over g

        // xb gather: only dependent/random load, table is L2-resident
        const uint4* xr = (const uint4*)(xb + (size_t)src * FN);
        const uint4 q0 = xr[g];
        const uint4 q1 = xr[4 + g];

        const short8 a0 = *(const short8*)&q0;
        const short8 a1 = *(const short8*)&q1;
        const short8 a2 = *(const short8*)&qe;

        float sv[4];
#pragma unroll
        for (int b = 0; b < 4; ++b) {
            f32x4 acc = {0.f, 0.f, 0.f, 0.f};
            acc = __builtin_amdgcn_mfma_f32_16x16x32_bf16(a0, wf[0][b], acc, 0, 0, 0);
            acc = __builtin_amdgcn_mfma_f32_16x16x32_bf16(a1, wf[1][b], acc, 0, 0, 0);
            acc = __builtin_amdgcn_mfma_f32_16x16x32_bf16(a2, wf[2][b], acc, 0, 0, 0);
            float s = 0.0f;
#pragma unroll
            for (int q = 0; q < 4; ++q) {
                const int row = w * 16 + 4 * g + q;
                const float v = fmaxf(acc[q] + bias[b], 0.0f);
                s += (row < end) ? v : 0.0f;
            }
            s += __shfl_xor(s, 16);
            s += __shfl_xor(s, 32);
            sv[b] = s;
        }
        float v = sv[0];
        v = (g == 1) ? sv[1] : v;
        v = (g == 2) ? sv[2] : v;
        v = (g == 3) ? sv[3] : v;

        // pack col pairs (l even: cols l, l+1) -> 128 B per window
        const float vn = __shfl_xor(v, 1);
        if ((l & 1) == 0)
            partial32[(size_t)w * 32 + (l >> 1)] = pack_bf16(v, vn);
    }
}

// ---------------------------------------------------------------------------
// Reduce windows per node (2 nodes per wave): aggb[n] = bf16(sum partials).
// Lane l: node base+(l>>5), col-pair q = l&31 (cols 2q, 2q+1).
// ---------------------------------------------------------------------------
__global__ __launch_bounds__(256) void k_red(const unsigned* __restrict__ partial32,
                                             const int* __restrict__ pstart,
                                             unsigned* __restrict__ aggb32) {
    const int l = threadIdx.x & 63;
    const int q = l & 31;
    int nb = (blockIdx.x * blockDim.x + threadIdx.x) >> 6;
    nb = __builtin_amdgcn_readfirstlane(nb);
    const int n = 2 * nb + (l >> 5);
    if (n >= NN) return;

    const int w0 = pstart[n] >> 4;
    const int w1 = pstart[n + 1] >> 4;
    float c0 = 0.0f, c1 = 0.0f;
    for (int w = w0; w < w1; ++w) {
        const unsigned uu = partial32[(size_t)w * 32 + q];
        c0 += __uint_as_float(uu << 16);
        c1 += __uint_as_float(uu & 0xffff0000u);
    }
    aggb32[(size_t)n * 32 + q] = pack_bf16(c0, c1);
}

// ---------------------------------------------------------------------------
// Node MLP via MFMA: out = relu([x_bf16 | agg_bf16] @ W2[0:128] + uW2b[batch])
// ---------------------------------------------------------------------------
__global__ __launch_bounds__(256) void k_nodem(const unsigned short* __restrict__ xb,
                                               const unsigned short* __restrict__ aggb,
                                               const int* __restrict__ bat,
                                               const float* __restrict__ uW2b,
                                               const float* __restrict__ W2,
                                               float* __restrict__ out) {
    const int l = threadIdx.x & 63;
    const int g = l >> 4;
    const int c = l & 15;

    short8 wf[4][4];
#pragma unroll
    for (int t = 0; t < 4; ++t)
#pragma unroll
        for (int b = 0; b < 4; ++b)
#pragma unroll
            for (int i = 0; i < 8; i += 2) {
                const int k = 32 * t + 8 * g + i;
                const unsigned p = pack_bf16(W2[k * OD + (c + 16 * b)],
                                             W2[(k + 1) * OD + (c + 16 * b)]);
                ((unsigned*)&wf[t][b])[i / 2] = p;
            }

    int wv = (blockIdx.x * blockDim.x + threadIdx.x) >> 6;
    wv = __builtin_amdgcn_readfirstlane(wv);

    for (int w = wv; w < NWIN_N; w += NODE_WAVES) {
        const int n0 = w * 16;
        const uint4* xr = (const uint4*)(xb + (size_t)(n0 + c) * FN);
        const uint4* ar = (const uint4*)(aggb + (size_t)(n0 + c) * OD);
        uint4 qx0 = xr[g], qx1 = xr[4 + g];
        uint4 qa0 = ar[g], qa1 = ar[4 + g];
        short8 a0 = *(short8*)&qx0, a1 = *(short8*)&qx1;
        short8 a2 = *(short8*)&qa0, a3 = *(short8*)&qa1;

        int bq[4];
#pragma unroll
        for (int q = 0; q < 4; ++q) bq[q] = bat[n0 + g * 4 + q];

#pragma unroll
        for (int b = 0; b < 4; ++b) {
            f32x4 acc = {0.f, 0.f, 0.f, 0.f};
            acc = __builtin_amdgcn_mfma_f32_16x16x32_bf16(a0, wf[0][b], acc, 0, 0, 0);
            acc = __builtin_amdgcn_mfma_f32_16x16x32_bf16(a1, wf[1][b], acc, 0, 0, 0);
            acc = __builtin_amdgcn_mfma_f32_16x16x32_bf16(a2, wf[2][b], acc, 0, 0, 0);
            acc = __builtin_amdgcn_mfma_f32_16x16x32_bf16(a3, wf[3][b], acc, 0, 0, 0);
#pragma unroll
            for (int q = 0; q < 4; ++q) {
                const int n = n0 + g * 4 + q;
                const float val = acc[q] + uW2b[(size_t)bq[q] * OD + c + 16 * b];
                out[(size_t)n * OD + c + 16 * b] = fmaxf(val, 0.0f);
            }
        }
    }
}

// ---------------------------------------------------------------------------
extern "C" void kernel_launch(void* const* d_in, const int* in_sizes, int n_in,
                              void* d_out, int out_size, void* d_ws, size_t ws_size,
                              hipStream_t stream) {
    const float* x    = (const float*)d_in[0];   // (50000, 64)
    const int*   ei   = (const int*)d_in[1];     // (2, 800000)
    const float* ea   = (const float*)d_in[2];   // (800000, 32)
    const float* u    = (const float*)d_in[3];   // (256, 32)
    const int*   bat  = (const int*)d_in[4];     // (50000,)
    const float* W1   = (const float*)d_in[5];   // (96, 64)
    const float* b1   = (const float*)d_in[6];   // (64,)
    const float* W2   = (const float*)d_in[7];   // (160, 64)
    const float* b2   = (const float*)d_in[8];   // (64,)
    float* out = (float*)d_out;                  // (50000, 64)

    // workspace layout (~116 MB; bucket_ea dominates)
    char* ws = (char*)d_ws;
    auto alloc = [&](size_t bytes) {
        char* p = ws;
        ws += (bytes + 255) & ~size_t(255);
        return p;
    };
    unsigned short* xb   = (unsigned short*)alloc((size_t)NN * FN * 2);     // 6.4 MB
    unsigned short* aggb = (unsigned short*)alloc((size_t)NN * OD * 2);     // 6.4 MB
    float* uW2b    = (float*)alloc((size_t)NG * OD * sizeof(float));
    int*   cnt     = (int*)alloc((size_t)NN * sizeof(int));
    int*   pstart  = (int*)alloc((size_t)(NN + 1) * sizeof(int));
    int*   cursor  = (int*)alloc((size_t)NN * sizeof(int));
    int*   bsum    = (int*)alloc((size_t)NBLK * sizeof(int));
    int*   winend  = (int*)alloc((size_t)NWIN_CAP * sizeof(int));           // 0.34 MB
    int*   bucket_src = (int*)alloc((size_t)SLOTS_CAP * sizeof(int));       // 5.4 MB
    uint4* bucket_ea  = (uint4*)alloc((size_t)SLOTS_CAP * 64);              // 86.4 MB
    unsigned* partial = (unsigned*)alloc((size_t)NWIN_CAP * 32 * 4);        // 10.8 MB

    // fused precompute (x->bf16, uW2b, zero cnt)
    k_pre<<<dim3(PRE_BLOCKS), dim3(256), 0, stream>>>(x, (unsigned*)xb, u, W2, b2, uW2b, cnt);

    // dst histogram + padded exclusive scan (+ per-window segment ends)
    k_hist<<<dim3((NE + 255) / 256), dim3(256), 0, stream>>>(ei, cnt);
    k_scan1<<<dim3(NBLK), dim3(SCAN_B), 0, stream>>>(cnt, pstart, bsum);
    k_scan23<<<dim3(NBLK), dim3(SCAN_B), 0, stream>>>(pstart, bsum, cnt, cursor, winend);

    // fat scatter: coalesced ea read -> bf16 payload into dst-sorted slots
    k_scat2<<<dim3((NE * 4 + 255) / 256), dim3(256), 0, stream>>>(ei, ea, cursor, bucket_src, bucket_ea);

    // sequential-read window MFMA + masked window sums
    k_aggw3<<<dim3(AGG_BLOCKS), dim3(256), 0, stream>>>(bucket_src, bucket_ea, xb, W1, b1,
                                                        pstart, winend, partial);

    // per-node reduce of window partials (2 nodes/wave)
    k_red<<<dim3((NN * 32 + 255) / 256), dim3(256), 0, stream>>>(partial, pstart, (unsigned*)aggb);

    // node MLP (MFMA)
    k_nodem<<<dim3(NODE_BLOCKS), dim3(256), 0, stream>>>(xb, aggb, bat, uW2b, W2, out);
}